// Round 1
// baseline (21.563 us; speedup 1.0000x reference)
//
#include <hip/hip_runtime.h>

#define NBATCH   32
#define NCH      64
#define NNODE    4096
#define WW       97
#define NTHREADS 512

// fp32 value of np.linspace(-1,1,4)[2] (and -[1])
#define XNEG 0.33333334f

__global__ __launch_bounds__(NTHREADS)
void pw_lagrange_kernel(const float* __restrict__ x,
                        const float* __restrict__ w,
                        float* __restrict__ out) {
  constexpr float X1 = -XNEG, X2 = XNEG;
  // Lagrange denominators in fp32 (match reference node values)
  constexpr float D0 = (-1.0f - X1) * (-1.0f - X2) * (-2.0f);
  constexpr float D1 = (X1 + 1.0f) * (X1 - X2) * (X1 - 1.0f);
  constexpr float D2 = (X2 + 1.0f) * (X2 - X1) * (X2 - 1.0f);
  constexpr float D3 = 2.0f * (1.0f - X1) * (1.0f - X2);
  constexpr float RD0 = 1.0f / D0, RD1 = 1.0f / D1, RD2 = 1.0f / D2, RD3 = 1.0f / D3;

  // ids of the transposed source row, [u][c] padded to 65 (2-way bank alias = free)
  __shared__ unsigned short sid[64 * 65];
  // pre-scaled weight windows: wexp[c*32 + id] = {w[c][3id+j] * RDj}
  __shared__ float4 wexp[NCH * 32];

  const int g   = blockIdx.x;
  const int b   = g >> 6;   // batch
  const int t   = g & 63;   // 64-wide nn block
  const int tid = threadIdx.x;

  // ---- Phase A1: bin ids of source row x[b][t][0:4096] ----
  const float* xrow = x + (((size_t)(b * NCH + t)) << 12);
  #pragma unroll
  for (int k = 0; k < 8; ++k) {
    const int s    = tid + k * NTHREADS;
    const float xs = xrow[s];
    const float tt = (xs + 1.0f) / 2.0f * 32.0f;   // exact: 16*(x+1)
    int id = (int)tt;                               // trunc toward zero (matches jnp.trunc+cast)
    id = id < 0 ? 0 : (id > 31 ? 31 : id);
    sid[(s >> 6) * 65 + (s & 63)] = (unsigned short)id;
  }

  // ---- Phase A2: expand + prescale weights into LDS ----
  #pragma unroll
  for (int k = 0; k < 4; ++k) {
    const int r = tid + k * NTHREADS;   // [0, 2048)
    const int c = r >> 5, i = r & 31;
    const float* wr = w + c * WW + 3 * i;
    wexp[r] = make_float4(wr[0] * RD0, wr[1] * RD1, wr[2] * RD2, wr[3] * RD3);
  }
  __syncthreads();

  // ---- Phase B: 8 waves x 8 channels, lane = u (nn within block) ----
  const int u  = tid & 63;
  const int wv = tid >> 6;
  const int c0 = wv << 3;
  const size_t base = (((size_t)(b * NCH + c0)) << 12) + ((size_t)(t << 6)) + u;

  float xv[8];
  #pragma unroll
  for (int k = 0; k < 8; ++k) xv[k] = x[base + ((size_t)k << 12)];

  #pragma unroll
  for (int k = 0; k < 8; ++k) {
    const int c    = c0 + k;
    const float xs = xv[k];

    // own bin id -> local coordinate x_in (bitwise-identical to reference)
    const float tt = (xs + 1.0f) / 2.0f * 32.0f;
    int idm = (int)tt;
    idm = idm < 0 ? 0 : (idm > 31 ? 31 : idm);
    const float xmin = fmaf((float)idm, 0.0625f, -1.0f);  // id/32*2 - 1
    const float xin  = fmaf(xs - xmin, 32.0f, -1.0f);     // 2*((x-xmin)/0.0625) - 1

    // transposed id -> weight window (single ds_read_b128)
    const int idw    = (int)sid[u * 65 + c];
    const float4 wv4 = wexp[(c << 5) + idw];

    // Lagrange basis numerators (denominators folded into wexp)
    const float t0  = xin + 1.0f;
    const float t1  = xin + XNEG;
    const float t2  = xin - XNEG;
    const float t3  = xin - 1.0f;
    const float u01 = t0 * t1, u23 = t2 * t3;
    const float p0  = t1 * u23;
    const float p1  = t0 * u23;
    const float p2  = u01 * t3;
    const float p3  = u01 * t2;

    out[base + ((size_t)k << 12)] =
        fmaf(p3, wv4.w, fmaf(p2, wv4.z, fmaf(p1, wv4.y, p0 * wv4.x)));
  }
}

extern "C" void kernel_launch(void* const* d_in, const int* in_sizes, int n_in,
                              void* d_out, int out_size, void* d_ws, size_t ws_size,
                              hipStream_t stream) {
  const float* x = (const float*)d_in[0];
  const float* w = (const float*)d_in[1];
  float* out    = (float*)d_out;
  dim3 grid(NBATCH * (NNODE / 64));
  pw_lagrange_kernel<<<grid, NTHREADS, 0, stream>>>(x, w, out);
}

// Round 3
// 20.463 us; speedup vs baseline: 1.0537x; 1.0537x over previous
//
#include <hip/hip_runtime.h>

#define NBATCH   32
#define NCH      64
#define NNODE    4096
#define WW       97
#define NTHREADS 512

// fp32 value of np.linspace(-1,1,4)[2] (and -[1])
#define XNEG 0.33333334f

typedef float f32x4 __attribute__((ext_vector_type(4)));

__global__ __launch_bounds__(NTHREADS)
void pw_lagrange_kernel(const float* __restrict__ x,
                        const float* __restrict__ w,
                        float* __restrict__ out) {
  constexpr float X1 = -XNEG, X2 = XNEG;
  constexpr float D0 = (-1.0f - X1) * (-1.0f - X2) * (-2.0f);
  constexpr float D1 = (X1 + 1.0f) * (X1 - X2) * (X1 - 1.0f);
  constexpr float D2 = (X2 + 1.0f) * (X2 - X1) * (X2 - 1.0f);
  constexpr float D3 = 2.0f * (1.0f - X1) * (1.0f - X2);
  constexpr float RD0 = 1.0f / D0, RD1 = 1.0f / D1, RD2 = 1.0f / D2, RD3 = 1.0f / D3;

  // transposed id table: sid2[c][u], uchar, stride 68 (rows 4B-aligned; 4 WGs/CU)
  __shared__ __align__(4) unsigned char sid2[NCH * 68];
  // pre-scaled weight windows: wexp[c*32 + id] = {w[c][3id+j] * RDj}
  __shared__ f32x4 wexp[NCH * 32];

  const int g   = blockIdx.x;
  const int b   = g >> 6;   // batch
  const int t   = g & 63;   // 64-wide nn block
  const int tid = threadIdx.x;

  // ---- Phase A1: bin ids of source row x[b][t][0:4096], float4 loads ----
  const float* xrow = x + (((size_t)(b * NCH + t)) << 12);
  #pragma unroll
  for (int k = 0; k < 2; ++k) {
    const int s4 = (tid + k * NTHREADS) << 2;          // 4-aligned s
    const f32x4 xq = *reinterpret_cast<const f32x4*>(xrow + s4);
    const int u  = s4 >> 6;
    const int cb = s4 & 63;
    #pragma unroll
    for (int i = 0; i < 4; ++i) {
      const float tt = (xq[i] + 1.0f) * 16.0f;         // == (x+1)/2*32 bitwise
      int id = (int)tt;                                // trunc toward zero
      id = id < 0 ? 0 : (id > 31 ? 31 : id);
      sid2[(cb + i) * 68 + u] = (unsigned char)id;
    }
  }

  // ---- Phase A2: expand + prescale weights into LDS ----
  #pragma unroll
  for (int k = 0; k < 4; ++k) {
    const int r = tid + k * NTHREADS;   // [0, 2048)
    const int c = r >> 5, i = r & 31;
    const float* wr = w + c * WW + 3 * i;
    f32x4 v;
    v[0] = wr[0] * RD0; v[1] = wr[1] * RD1; v[2] = wr[2] * RD2; v[3] = wr[3] * RD3;
    wexp[r] = v;
  }
  __syncthreads();

  // ---- Phase B: thread owns 4 consecutive nn (float4), 2 channel passes ----
  const int l  = tid & 63;
  const int wv = tid >> 6;
  const int q  = l & 15;      // nn quad index
  const int cg = l >> 4;      // channel subgroup 0..3
  const int u0 = q << 2;

  #pragma unroll
  for (int p = 0; p < 2; ++p) {
    const int c = cg + (wv << 2) + (p << 5);
    const size_t base = (((size_t)(b * NCH + c)) << 12) + ((size_t)(t << 6)) + u0;

    const f32x4 xq = *reinterpret_cast<const f32x4*>(x + base);
    // 4 transposed ids in one LDS dword
    const unsigned int ids4 =
        *reinterpret_cast<const unsigned int*>(&sid2[c * 68 + u0]);

    f32x4 res;
    #pragma unroll
    for (int i = 0; i < 4; ++i) {
      const float xv = xq[i];
      // own bin id -> local coordinate (bitwise-identical to reference)
      const float tt = (xv + 1.0f) * 16.0f;
      int idm = (int)tt;
      idm = idm < 0 ? 0 : (idm > 31 ? 31 : idm);
      const float xmin = fmaf((float)idm, 0.0625f, -1.0f);
      const float xin  = fmaf(xv - xmin, 32.0f, -1.0f);

      const int idw   = (ids4 >> (8 * i)) & 0xff;
      const f32x4 w4  = wexp[(c << 5) + idw];

      const float t0  = xin + 1.0f;
      const float t1  = xin + XNEG;
      const float t2  = xin - XNEG;
      const float t3  = xin - 1.0f;
      const float u01 = t0 * t1, u23 = t2 * t3;
      const float p0  = t1 * u23;
      const float p1  = t0 * u23;
      const float p2  = u01 * t3;
      const float p3  = u01 * t2;

      res[i] = fmaf(p3, w4[3], fmaf(p2, w4[2], fmaf(p1, w4[1], p0 * w4[0])));
    }
    __builtin_nontemporal_store(res, reinterpret_cast<f32x4*>(out + base));
  }
}

extern "C" void kernel_launch(void* const* d_in, const int* in_sizes, int n_in,
                              void* d_out, int out_size, void* d_ws, size_t ws_size,
                              hipStream_t stream) {
  const float* x = (const float*)d_in[0];
  const float* w = (const float*)d_in[1];
  float* out    = (float*)d_out;
  dim3 grid(NBATCH * (NNODE / 64));
  pw_lagrange_kernel<<<grid, NTHREADS, 0, stream>>>(x, w, out);
}